// Round 8
// baseline (3916.500 us; speedup 1.0000x reference)
//
#include <hip/hip_runtime.h>

// Problem constants
#define NB 8
#define NT 1024
#define ND 768     // = 12*64
#define NH 12
#define NU 64
#define BT (NB*NT)   // 8192
#define SCALE32 ((float)0.03608439182435161)  // fp32(768^-0.5)
#define EPS32 1e-7f

// ---------------------------------------------------------------------------
// 4-way dot-split (p-split): the reference dot64's r[0..3] accumulator
// chains are independent (stride-4). Thread p of a row computes EXACTLY
// chain r[p] over its q/k slices (16 named floats each — no arrays, nothing
// scratch-demotable). Reduce via quad shuffles:
//   tt = fadd(rp, shfl_xor(rp,2)); dt = fadd(tt, shfl_xor(tt,1));
// at p=0 this is fadd(fadd(r0,r2), fadd(r1,r3)) — the reference reduce,
// self-always-left. IEEE fadd is COMMUTATIVE bitwise, so all 4 lanes hold
// identical dt. K/V/MF addresses depend only on (s,p): one 16B transaction
// per load instruction.
// ---------------------------------------------------------------------------
#define QSLICE_LOAD(ptr) \
    const float q0=(ptr)[0],  q1=(ptr)[4],  q2=(ptr)[8],   q3=(ptr)[12], \
                q4=(ptr)[16], q5=(ptr)[20], q6=(ptr)[24],  q7=(ptr)[28], \
                q8=(ptr)[32], q9=(ptr)[36], q10=(ptr)[40], q11=(ptr)[44], \
                q12=(ptr)[48],q13=(ptr)[52],q14=(ptr)[56], q15=(ptr)[60];

#define DOTP(kp, dt) \
    float rp = __fmul_rn(q0, (kp)[0]); \
    rp = __fadd_rn(rp, __fmul_rn(q1,  (kp)[4]));  \
    rp = __fadd_rn(rp, __fmul_rn(q2,  (kp)[8]));  \
    rp = __fadd_rn(rp, __fmul_rn(q3,  (kp)[12])); \
    rp = __fadd_rn(rp, __fmul_rn(q4,  (kp)[16])); \
    rp = __fadd_rn(rp, __fmul_rn(q5,  (kp)[20])); \
    rp = __fadd_rn(rp, __fmul_rn(q6,  (kp)[24])); \
    rp = __fadd_rn(rp, __fmul_rn(q7,  (kp)[28])); \
    rp = __fadd_rn(rp, __fmul_rn(q8,  (kp)[32])); \
    rp = __fadd_rn(rp, __fmul_rn(q9,  (kp)[36])); \
    rp = __fadd_rn(rp, __fmul_rn(q10, (kp)[40])); \
    rp = __fadd_rn(rp, __fmul_rn(q11, (kp)[44])); \
    rp = __fadd_rn(rp, __fmul_rn(q12, (kp)[48])); \
    rp = __fadd_rn(rp, __fmul_rn(q13, (kp)[52])); \
    rp = __fadd_rn(rp, __fmul_rn(q14, (kp)[56])); \
    rp = __fadd_rn(rp, __fmul_rn(q15, (kp)[60])); \
    const float tt = __fadd_rn(rp, __shfl_xor(rp, 2, 64)); \
    const float dt = __fadd_rn(tt, __shfl_xor(tt, 1, 64));

// ---------------------------------------------------------------------------
// Mask decode with byte/int32 layout sniff (mask is all-ones in practice).
// ---------------------------------------------------------------------------
__global__ __launch_bounds__(256) void mask_k(
    const unsigned char* __restrict__ mb, float* __restrict__ mf)
{
    __shared__ int cntOff, cntAll;
    if (threadIdx.x == 0) { cntOff = 0; cntAll = 0; }
    __syncthreads();
    int lo = 0, la = 0;
    for (int i = threadIdx.x; i < BT; i += 256)
        if (mb[i] != 0) { la++; if ((i & 3) != 0) lo++; }
    atomicAdd(&cntOff, lo);
    atomicAdd(&cntAll, la);
    __syncthreads();
    const bool int32mode = (cntOff == 0) && (cntAll != 0);
    if (int32mode) {
        const int* mi = (const int*)mb;
        for (int i = threadIdx.x; i < BT; i += 256)
            mf[i] = (mi[i] != 0) ? 1.f : 0.f;
    } else {
        for (int i = threadIdx.x; i < BT; i += 256)
            mf[i] = (mb[i] != 0) ? 1.f : 0.f;
    }
}

// ---------------------------------------------------------------------------
// OpenBLAS-mimic sgemm: C = A[8192x768] @ W[768x768] (+R elementwise after).
// R7 analysis: the 4x4 micro (2 ds_read_b128 per 16 fma) is LDS-pipe-bound
// (~92us LDS vs 61us VALU). New: 128x64 tile, 8x4 micro — 3 b128 per 32 fma,
// LDS-read insts halved. grid (64,12) = 768 blocks = exactly 3/CU (50KB LDS
// x3 = 150KB of 160). Per-output chain still fma over k ascending 0..767
// with the kc=384 panel split — bitwise-identical to the 4x4 version.
// ---------------------------------------------------------------------------
__global__ __launch_bounds__(256) void gemmseq(
    const float* __restrict__ A, const float* __restrict__ W,
    const float* __restrict__ R, float* __restrict__ C)
{
    __shared__ float sA[64][132];  // [k][m], transposed, 128 m + 4 pad
    __shared__ float sB[64][68];   // [k][n]

    const int t = threadIdx.x;
    const int mbase = blockIdx.x * 128;
    const int nbase = blockIdx.y * 64;
    const int m0 = (t >> 4) * 8;
    const int n0 = (t & 15) * 4;

    float acc[8][4], accA[8][4];
#pragma unroll
    for (int i = 0; i < 8; i++)
#pragma unroll
        for (int j = 0; j < 4; j++) { acc[i][j] = 0.f; accA[i][j] = 0.f; }

    for (int k0 = 0; k0 < 768; k0 += 64) {
        __syncthreads();
#pragma unroll
        for (int i = 0; i < 8; i++) {           // A tile: 128 rows x 64 k
            const int idx = t + i * 256;        // 0..2047
            const int ar = idx >> 4;            // 0..127
            const int ak4 = (idx & 15) * 4;     // 0..60
            const float4 a4 = *(const float4*)&A[(size_t)(mbase + ar) * 768 + k0 + ak4];
            sA[ak4 + 0][ar] = a4.x;
            sA[ak4 + 1][ar] = a4.y;
            sA[ak4 + 2][ar] = a4.z;
            sA[ak4 + 3][ar] = a4.w;
        }
#pragma unroll
        for (int i = 0; i < 4; i++) {           // B tile: 64 rows x 64 n
            const int idx = t + i * 256;        // 0..1023
            const int br = idx >> 4;            // 0..63
            const int bk4 = (idx & 15) * 4;     // 0..60
            *(float4*)&sB[br][bk4] =
                *(const float4*)&W[(size_t)(k0 + br) * 768 + nbase + bk4];
        }
        __syncthreads();

        for (int kk = 0; kk < 64; kk++) {
            float av[8], bv[4];
            *(float4*)&av[0] = *(const float4*)&sA[kk][m0];
            *(float4*)&av[4] = *(const float4*)&sA[kk][m0 + 4];
            *(float4*)&bv[0] = *(const float4*)&sB[kk][n0];
#pragma unroll
            for (int i = 0; i < 8; i++)
#pragma unroll
                for (int j = 0; j < 4; j++)
                    acc[i][j] = fmaf(av[i], bv[j], acc[i][j]);
        }

        if (k0 + 64 == 384) {   // end of first kc panel (OpenBLAS kc=384)
#pragma unroll
            for (int i = 0; i < 8; i++)
#pragma unroll
                for (int j = 0; j < 4; j++) {
                    accA[i][j] = acc[i][j];
                    acc[i][j] = 0.f;
                }
        }
    }

#pragma unroll
    for (int i = 0; i < 8; i++)
#pragma unroll
        for (int j = 0; j < 4; j++) {
            const size_t idx = (size_t)(mbase + m0 + i) * 768 + nbase + n0 + j;
            float o = __fadd_rn(accA[i][j], acc[i][j]);  // C = panel0 + panel1
            if (R) o = __fadd_rn(o, R[idx]);             // np: out = tmp + x
            C[idx] = o;
        }
}

// ---------------------------------------------------------------------------
// Denominator, p-split: 4 threads/row (lane = 4*rowInWave + p). Each thread
// runs chain r[p]; quad-shuffle reduce gives identical dt on all 4 lanes
// (commutativity). b8 chains: inner 8-step groups unrolled so j is static ->
// 8 NAMED floats, duplicated identically across the 4 p-lanes (free, SIMT).
// s order: c ascending, k ascending, j ascending = exact serial order.
// Bi[8] array is cold (8 accesses/thread). Write at p==0.
// 64 rows/block (one bh spans 16 blocks), grid 1536, XCD-swizzled.
// ---------------------------------------------------------------------------
#define DEN_STEP(J, KOFF, INIT) { \
    const int s = sb + (KOFF) * 8 + (J); \
    const float* kp = Kb + (size_t)s * ND + p; \
    DOTP(kp, dt) \
    float sc = __fmul_rn(dt, SCALE32); \
    sc = __fmul_rn(sc, MFb[s]); \
    sc = __fmul_rn(sc, mq); \
    if (INIT) b8_##J = sc; \
    else      b8_##J = __fadd_rn(b8_##J, sc); \
}

__global__ __launch_bounds__(256) void denom_p(
    const float* __restrict__ Q, const float* __restrict__ K,
    const float* __restrict__ MF, float* __restrict__ D)
{
    const int bid = blockIdx.x;
    const int lb  = (bid & 7) * 192 + (bid >> 3);    // XCD-grouped (1536%8==0)
    const int t   = threadIdx.x;
    const int rowg = lb * 64 + (t >> 2);             // 0..98303
    const int p   = t & 3;
    const int bh  = rowg >> 10;
    const int row = rowg & 1023;
    const int b = bh / NH, h = bh % NH;

    const float mq = MF[b * NT + row];

    const float* Qrow = &Q[((size_t)(b * NT + row)) * ND + h * 64] + p;
    QSLICE_LOAD(Qrow)

    const float* Kb  = &K[((size_t)(b * NT)) * ND + h * 64];
    const float* MFb = &MF[b * NT];

    float Bi[8];
    for (int c = 0; c < 8; c++) {
        const int sb = c * 128;
        float b8_0, b8_1, b8_2, b8_3, b8_4, b8_5, b8_6, b8_7;
        DEN_STEP(0, 0, 1) DEN_STEP(1, 0, 1) DEN_STEP(2, 0, 1) DEN_STEP(3, 0, 1)
        DEN_STEP(4, 0, 1) DEN_STEP(5, 0, 1) DEN_STEP(6, 0, 1) DEN_STEP(7, 0, 1)
        for (int k = 1; k < 16; k++) {
            DEN_STEP(0, k, 0) DEN_STEP(1, k, 0) DEN_STEP(2, k, 0) DEN_STEP(3, k, 0)
            DEN_STEP(4, k, 0) DEN_STEP(5, k, 0) DEN_STEP(6, k, 0) DEN_STEP(7, k, 0)
        }
        Bi[c] = __fadd_rn(
            __fadd_rn(__fadd_rn(b8_0, b8_1), __fadd_rn(b8_2, b8_3)),
            __fadd_rn(__fadd_rn(b8_4, b8_5), __fadd_rn(b8_6, b8_7)));
    }

    if (p == 0)
        D[(size_t)bh * NT + row] = __fadd_rn(
            __fadd_rn(__fadd_rn(Bi[0], Bi[1]), __fadd_rn(Bi[2], Bi[3])),
            __fadd_rn(__fadd_rn(Bi[4], Bi[5]), __fadd_rn(Bi[6], Bi[7])));
}

// ---------------------------------------------------------------------------
// Attention out, p-split: 4 threads/row. Thread p: chain r[p] of the dot
// (identical dt on all 4 lanes after quad reduce), identical score/divide,
// then OWNS output chains j in {p, 4+p, ..., 60+p}: 16 named o accumulators,
// each a full serial chain over s ascending — exact reference order per j.
// Hot state = 32 named floats (q-slice + o-slice): fits VGPRs trivially.
// V/MF addresses = f(s,p): one 16B transaction per instruction.
// Self-alias safe: q-slice read once before loop (wave-lockstep), o written
// after; each output dword has exactly one owner.
// 64 rows/block, grid 1536, XCD-swizzled.
// ---------------------------------------------------------------------------
#define AXPY_P(JJ) o##JJ = __fadd_rn(o##JJ, __fmul_rn(pv, vp[4*(JJ)]));

__global__ __launch_bounds__(256) void attn_p(
    const float* __restrict__ K, const float* __restrict__ V,
    const float* __restrict__ D, const float* __restrict__ MF,
    float* __restrict__ QA)   // in: Q, out: A (self-aliased per row)
{
    const int bid = blockIdx.x;
    const int lb  = (bid & 7) * 192 + (bid >> 3);    // XCD-grouped
    const int t   = threadIdx.x;
    const int rowg = lb * 64 + (t >> 2);
    const int p   = t & 3;
    const int bh  = rowg >> 10;
    const int row = rowg & 1023;
    const int b = bh / NH, h = bh % NH;

    const float mq = MF[b * NT + row];
    const float De = __fadd_rn(D[(size_t)bh * NT + row], EPS32);  // np: sum+eps

    const float* Qrow = &QA[((size_t)(b * NT + row)) * ND + h * 64] + p;
    QSLICE_LOAD(Qrow)

    float o0=0.f, o1=0.f, o2=0.f,  o3=0.f,  o4=0.f,  o5=0.f,  o6=0.f,  o7=0.f,
          o8=0.f, o9=0.f, o10=0.f, o11=0.f, o12=0.f, o13=0.f, o14=0.f, o15=0.f;

    const float* Kb  = &K[((size_t)(b * NT)) * ND + h * 64];
    const float* Vb  = &V[((size_t)(b * NT)) * ND + h * 64];
    const float* MFb = &MF[b * NT];

    for (int s = 0; s < NT; s++) {
        const float* kp = Kb + (size_t)s * ND + p;
        DOTP(kp, dt)
        float sc = __fmul_rn(dt, SCALE32);
        sc = __fmul_rn(sc, MFb[s]);
        sc = __fmul_rn(sc, mq);
        const float pv = __fdiv_rn(sc, De);
        const float* vp = Vb + (size_t)s * ND + p;
        AXPY_P(0)  AXPY_P(1)  AXPY_P(2)  AXPY_P(3)
        AXPY_P(4)  AXPY_P(5)  AXPY_P(6)  AXPY_P(7)
        AXPY_P(8)  AXPY_P(9)  AXPY_P(10) AXPY_P(11)
        AXPY_P(12) AXPY_P(13) AXPY_P(14) AXPY_P(15)
    }

    float* Arow = &QA[((size_t)(b * NT + row)) * ND + h * 64] + p;
    Arow[0]  = o0;  Arow[4]  = o1;  Arow[8]  = o2;  Arow[12] = o3;
    Arow[16] = o4;  Arow[20] = o5;  Arow[24] = o6;  Arow[28] = o7;
    Arow[32] = o8;  Arow[36] = o9;  Arow[40] = o10; Arow[44] = o11;
    Arow[48] = o12; Arow[52] = o13; Arow[56] = o14; Arow[60] = o15;
}

// ---------------------------------------------------------------------------
// Row norm, numpy-faithful pairwise mean via ONE WAVE per row (unchanged).
// ---------------------------------------------------------------------------
__global__ __launch_bounds__(256) void rownorm_np(
    float* __restrict__ Y, const float* __restrict__ gamma,
    const float* __restrict__ beta)
{
    const int wave = threadIdx.x >> 6, lane = threadIdx.x & 63;
    const int row = blockIdx.x * 4 + wave;
    float* yr = Y + (size_t)row * ND;
    const int c = lane >> 3, j = lane & 7;

    const float* a = yr + c * 96;
    float r = a[j];
#pragma unroll
    for (int i = 1; i < 12; i++) r = __fadd_rn(r, a[i * 8 + j]);

    // j-tree within base-96 block, then c-tree across blocks (bitwise = R9)
    r = __fadd_rn(r, __shfl_xor(r, 1, 64));
    r = __fadd_rn(r, __shfl_xor(r, 2, 64));
    r = __fadd_rn(r, __shfl_xor(r, 4, 64));
    r = __fadd_rn(r, __shfl_xor(r, 8, 64));
    r = __fadd_rn(r, __shfl_xor(r, 16, 64));
    r = __fadd_rn(r, __shfl_xor(r, 32, 64));

    const float m = __fdiv_rn(r, 768.0f);
    const float mpe = __fadd_rn(m, EPS32);

#pragma unroll
    for (int i = 0; i < 12; i++) {
        const int idx = i * 64 + lane;
        const float v = yr[idx];
        float o = __fsub_rn(v, m);
        o = __fmul_rn(gamma[idx], o);
        o = __fdiv_rn(o, mpe);
        o = __fadd_rn(o, beta[idx]);
        yr[idx] = o;
    }
}

// ---------------------------------------------------------------------------
extern "C" void kernel_launch(void* const* d_in, const int* in_sizes, int n_in,
                              void* d_out, int out_size, void* d_ws, size_t ws_size,
                              hipStream_t stream)
{
    (void)in_sizes; (void)n_in; (void)out_size; (void)ws_size;
    const float* x     = (const float*)d_in[0];
    const unsigned char* maskb = (const unsigned char*)d_in[1];
    const float* wq    = (const float*)d_in[2];
    const float* wk    = (const float*)d_in[3];
    const float* wv    = (const float*)d_in[4];
    const float* wf    = (const float*)d_in[5];
    const float* gamma = (const float*)d_in[6];
    const float* beta  = (const float*)d_in[7];

    float* ws = (float*)d_ws;
    float* MF = ws;                             // 8192
    float* D  = MF + BT;                        // 96*1024
    float* Q  = D + (size_t)96 * NT;            // 8192*768 (becomes A)
    float* K  = Q + (size_t)BT * ND;            // 8192*768
    float* V  = K + (size_t)BT * ND;            // 8192*768
    float* Y  = (float*)d_out;                  // total ws: 75.9 MB

    mask_k<<<1, 256, 0, stream>>>(maskb, MF);
    gemmseq<<<dim3(64, 12), 256, 0, stream>>>(x, wq, nullptr, Q);
    gemmseq<<<dim3(64, 12), 256, 0, stream>>>(x, wk, nullptr, K);
    gemmseq<<<dim3(64, 12), 256, 0, stream>>>(x, wv, nullptr, V);
    denom_p<<<1536, 256, 0, stream>>>(Q, K, MF, D);
    attn_p<<<1536, 256, 0, stream>>>(K, V, D, MF, Q);  // Q -> A
    gemmseq<<<dim3(64, 12), 256, 0, stream>>>(Q, wf, x, Y);
    rownorm_np<<<2048, 256, 0, stream>>>(Y, gamma, beta);
}

// Round 9
// 1725.092 us; speedup vs baseline: 2.2703x; 2.2703x over previous
//
#include <hip/hip_runtime.h>

// Problem constants
#define NB 8
#define NT 1024
#define ND 768     // = 12*64
#define NH 12
#define NU 64
#define BT (NB*NT)   // 8192
#define SCALE32 ((float)0.03608439182435161)  // fp32(768^-0.5)
#define EPS32 1e-7f

// ---------------------------------------------------------------------------
// numpy baseline-SIMD (SSE2, no FMA) einsum dot over 64 contiguous elements:
// 4 accumulators stride-4, separate mul/add (rounded each), reduce
// (r0+r2)+(r1+r3). __f*_rn blocks hipcc contraction. BITWISE-IDENTICAL.
// ---------------------------------------------------------------------------
__device__ __forceinline__ float dot64_np(const float* a, const float* b)
{
    float r[4];
#pragma unroll
    for (int j = 0; j < 4; j++) r[j] = __fmul_rn(a[j], b[j]);
#pragma unroll
    for (int i = 1; i < 16; i++)
#pragma unroll
        for (int j = 0; j < 4; j++)
            r[j] = __fadd_rn(r[j], __fmul_rn(a[i * 4 + j], b[i * 4 + j]));
    return __fadd_rn(__fadd_rn(r[0], r[2]), __fadd_rn(r[1], r[3]));
}

// ---------------------------------------------------------------------------
// Mask decode with byte/int32 layout sniff (mask is all-ones in practice).
// ---------------------------------------------------------------------------
__global__ __launch_bounds__(256) void mask_k(
    const unsigned char* __restrict__ mb, float* __restrict__ mf)
{
    __shared__ int cntOff, cntAll;
    if (threadIdx.x == 0) { cntOff = 0; cntAll = 0; }
    __syncthreads();
    int lo = 0, la = 0;
    for (int i = threadIdx.x; i < BT; i += 256)
        if (mb[i] != 0) { la++; if ((i & 3) != 0) lo++; }
    atomicAdd(&cntOff, lo);
    atomicAdd(&cntAll, la);
    __syncthreads();
    const bool int32mode = (cntOff == 0) && (cntAll != 0);
    if (int32mode) {
        const int* mi = (const int*)mb;
        for (int i = threadIdx.x; i < BT; i += 256)
            mf[i] = (mi[i] != 0) ? 1.f : 0.f;
    } else {
        for (int i = threadIdx.x; i < BT; i += 256)
            mf[i] = (mb[i] != 0) ? 1.f : 0.f;
    }
}

// ---------------------------------------------------------------------------
// OpenBLAS-mimic sgemm: C = A[8192x768] @ W[768x768] (+R elementwise after).
// 128x64 tile, 8x4 micro: 3 ds_read_b128 per 32 fma (vs 2 per 16 in the
// 64x64/4x4 version) — LDS-read issue per FMA halved. Per-output chain is
// fmaf over k ascending with the kc=384 panel split — BITWISE-IDENTICAL to
// the 4x4 version (chain depends only on k order). LDS 51.2KB -> 3 blocks/CU
// (12 waves/CU, same occupancy as before). grid (64,12).
// ---------------------------------------------------------------------------
__global__ __launch_bounds__(256) void gemmseq(
    const float* __restrict__ A, const float* __restrict__ W,
    const float* __restrict__ R, float* __restrict__ C)
{
    __shared__ float sA[64][132];  // [k][m], transposed, 128 m + 4 pad
    __shared__ float sB[64][68];   // [k][n]

    const int t = threadIdx.x;
    const int mbase = blockIdx.x * 128;
    const int nbase = blockIdx.y * 64;
    const int m0 = (t >> 4) * 8;
    const int n0 = (t & 15) * 4;

    float acc[8][4], accA[8][4];
#pragma unroll
    for (int i = 0; i < 8; i++)
#pragma unroll
        for (int j = 0; j < 4; j++) { acc[i][j] = 0.f; accA[i][j] = 0.f; }

    for (int k0 = 0; k0 < 768; k0 += 64) {
        __syncthreads();
#pragma unroll
        for (int i = 0; i < 8; i++) {           // A tile: 128 rows x 64 k
            const int idx = t + i * 256;        // 0..2047
            const int ar = idx >> 4;            // 0..127
            const int ak4 = (idx & 15) * 4;     // 0..60
            const float4 a4 = *(const float4*)&A[(size_t)(mbase + ar) * 768 + k0 + ak4];
            sA[ak4 + 0][ar] = a4.x;
            sA[ak4 + 1][ar] = a4.y;
            sA[ak4 + 2][ar] = a4.z;
            sA[ak4 + 3][ar] = a4.w;
        }
#pragma unroll
        for (int i = 0; i < 4; i++) {           // B tile: 64 rows x 64 n
            const int idx = t + i * 256;        // 0..1023
            const int br = idx >> 4;            // 0..63
            const int bk4 = (idx & 15) * 4;     // 0..60
            *(float4*)&sB[br][bk4] =
                *(const float4*)&W[(size_t)(k0 + br) * 768 + nbase + bk4];
        }
        __syncthreads();

        for (int kk = 0; kk < 64; kk++) {
            float av[8], bv[4];
            *(float4*)&av[0] = *(const float4*)&sA[kk][m0];
            *(float4*)&av[4] = *(const float4*)&sA[kk][m0 + 4];
            *(float4*)&bv[0] = *(const float4*)&sB[kk][n0];
#pragma unroll
            for (int i = 0; i < 8; i++)
#pragma unroll
                for (int j = 0; j < 4; j++)
                    acc[i][j] = fmaf(av[i], bv[j], acc[i][j]);
        }

        if (k0 + 64 == 384) {   // end of first kc panel (OpenBLAS kc=384)
#pragma unroll
            for (int i = 0; i < 8; i++)
#pragma unroll
                for (int j = 0; j < 4; j++) {
                    accA[i][j] = acc[i][j];
                    acc[i][j] = 0.f;
                }
        }
    }

#pragma unroll
    for (int i = 0; i < 8; i++)
#pragma unroll
        for (int j = 0; j < 4; j++) {
            const size_t idx = (size_t)(mbase + m0 + i) * 768 + nbase + n0 + j;
            float o = __fadd_rn(accA[i][j], acc[i][j]);  // C = panel0 + panel1
            if (R) o = __fadd_rn(o, R[idx]);             // np: out = tmp + x
            C[idx] = o;
        }
}

// ---------------------------------------------------------------------------
// Denominator: D[bh][t] = numpy pairwise_sum over s (8 base-128 blocks of
// 8 plain-add accumulators + tree). One THREAD per row, q in registers,
// k via wave-uniform scalar loads (readfirstlane-proven) — zero LDS.
// grid 768 x 128, XCD-swizzled (R2 champion form, measured in 1750 total).
// ---------------------------------------------------------------------------
__global__ __launch_bounds__(128) void denom_np(
    const float* __restrict__ Q, const float* __restrict__ K,
    const float* __restrict__ MF, float* __restrict__ D)
{
    const int bid = blockIdx.x;
    const int lb  = (bid & 7) * 96 + (bid >> 3);     // XCD-grouped logical id
    const int gid = lb * 128 + threadIdx.x;          // 0..98303
    const int bh = gid >> 10;                        // uniform per block
    const int row = gid & 1023;
    const int b = bh / NH, h = bh % NH;
    const int bh_u = __builtin_amdgcn_readfirstlane(bh);
    const int b_u = bh_u / NH, h_u = bh_u % NH;

    const float mq = MF[b * NT + row];

    float qr[64];
    const float4* qp = (const float4*)&Q[((size_t)(b * NT + row)) * ND + h * 64];
#pragma unroll
    for (int i = 0; i < 16; i++) *(float4*)&qr[i * 4] = qp[i];

    const float* Kb = &K[((size_t)(b_u * NT)) * ND + h_u * 64];
    const float* MFb = &MF[b_u * NT];

    float Bi[8];
    for (int c = 0; c < 8; c++) {
        float b8[8];
        for (int s = 0; s < 128; s++) {
            const int sg = c * 128 + s;
            const float dt = dot64_np(qr, Kb + (size_t)sg * ND); // uniform k
            float sc = __fmul_rn(dt, SCALE32);
            sc = __fmul_rn(sc, MFb[sg]);
            sc = __fmul_rn(sc, mq);
            const int j = s & 7;
            if (s < 8) b8[j] = sc;
            else       b8[j] = __fadd_rn(b8[j], sc);
        }
        Bi[c] = __fadd_rn(__fadd_rn(__fadd_rn(b8[0], b8[1]), __fadd_rn(b8[2], b8[3])),
                          __fadd_rn(__fadd_rn(b8[4], b8[5]), __fadd_rn(b8[6], b8[7])));
    }

    D[(size_t)bh * NT + row] = __fadd_rn(
        __fadd_rn(__fadd_rn(Bi[0], Bi[1]), __fadd_rn(Bi[2], Bi[3])),
        __fadd_rn(__fadd_rn(Bi[4], Bi[5]), __fadd_rn(Bi[6], Bi[7])));
}

// ---------------------------------------------------------------------------
// Attention out. One THREAD per row: q (64 regs), o[64] accumulators,
// k/v via wave-uniform scalar loads — zero LDS. XCD-swizzled blockIdx:
// 8 blocks per bh co-located per XCD -> K/V slices L2-resident (R2 champion
// form: 686us, FETCH 62MB). Scores recomputed with the bitwise-identical
// dot/mask/scale/divide sequence; o[u] chains over s ascending exactly as
// R9. Self-aliased QA. grid 768 x 128.
// ---------------------------------------------------------------------------
__global__ __launch_bounds__(128) void attn_np(
    const float* __restrict__ K, const float* __restrict__ V,
    const float* __restrict__ D, const float* __restrict__ MF,
    float* __restrict__ QA)   // in: Q, out: A (self-aliased per row)
{
    const int bid = blockIdx.x;
    const int lb  = (bid & 7) * 96 + (bid >> 3);     // XCD-grouped logical id
    const int gid = lb * 128 + threadIdx.x;
    const int bh = gid >> 10;
    const int row = gid & 1023;
    const int b = bh / NH, h = bh % NH;
    const int bh_u = __builtin_amdgcn_readfirstlane(bh);
    const int b_u = bh_u / NH, h_u = bh_u % NH;

    const float mq = MF[b * NT + row];
    const float De = __fadd_rn(D[(size_t)bh * NT + row], EPS32);  // np: sum+eps

    float qr[64];
    const float4* qp = (const float4*)&QA[((size_t)(b * NT + row)) * ND + h * 64];
#pragma unroll
    for (int i = 0; i < 16; i++) *(float4*)&qr[i * 4] = qp[i];

    float o[64];
#pragma unroll
    for (int j = 0; j < 64; j++) o[j] = 0.f;

    const float* Kb = &K[((size_t)(b_u * NT)) * ND + h_u * 64];
    const float* Vb = &V[((size_t)(b_u * NT)) * ND + h_u * 64];
    const float* MFb = &MF[b_u * NT];

    for (int s = 0; s < NT; s++) {
        const float dt = dot64_np(qr, Kb + (size_t)s * ND);  // uniform k
        float sc = __fmul_rn(dt, SCALE32);
        sc = __fmul_rn(sc, MFb[s]);
        sc = __fmul_rn(sc, mq);
        const float p = __fdiv_rn(sc, De);
        const float* vp = Vb + (size_t)s * ND;               // uniform v
#pragma unroll
        for (int j = 0; j < 64; j++)
            o[j] = __fadd_rn(o[j], __fmul_rn(p, vp[j]));     // np SSE2 axpy
    }

    float4* op = (float4*)&QA[((size_t)(b * NT + row)) * ND + h * 64];
#pragma unroll
    for (int i = 0; i < 16; i++) op[i] = *(float4*)&o[i * 4];
}

// ---------------------------------------------------------------------------
// Row norm, numpy-faithful pairwise mean via ONE WAVE per row (unchanged).
// ---------------------------------------------------------------------------
__global__ __launch_bounds__(256) void rownorm_np(
    float* __restrict__ Y, const float* __restrict__ gamma,
    const float* __restrict__ beta)
{
    const int wave = threadIdx.x >> 6, lane = threadIdx.x & 63;
    const int row = blockIdx.x * 4 + wave;
    float* yr = Y + (size_t)row * ND;
    const int c = lane >> 3, j = lane & 7;

    const float* a = yr + c * 96;
    float r = a[j];
#pragma unroll
    for (int i = 1; i < 12; i++) r = __fadd_rn(r, a[i * 8 + j]);

    // j-tree within base-96 block, then c-tree across blocks (bitwise = R9)
    r = __fadd_rn(r, __shfl_xor(r, 1, 64));
    r = __fadd_rn(r, __shfl_xor(r, 2, 64));
    r = __fadd_rn(r, __shfl_xor(r, 4, 64));
    r = __fadd_rn(r, __shfl_xor(r, 8, 64));
    r = __fadd_rn(r, __shfl_xor(r, 16, 64));
    r = __fadd_rn(r, __shfl_xor(r, 32, 64));

    const float m = __fdiv_rn(r, 768.0f);
    const float mpe = __fadd_rn(m, EPS32);

#pragma unroll
    for (int i = 0; i < 12; i++) {
        const int idx = i * 64 + lane;
        const float v = yr[idx];
        float o = __fsub_rn(v, m);
        o = __fmul_rn(gamma[idx], o);
        o = __fdiv_rn(o, mpe);
        o = __fadd_rn(o, beta[idx]);
        yr[idx] = o;
    }
}

// ---------------------------------------------------------------------------
extern "C" void kernel_launch(void* const* d_in, const int* in_sizes, int n_in,
                              void* d_out, int out_size, void* d_ws, size_t ws_size,
                              hipStream_t stream)
{
    (void)in_sizes; (void)n_in; (void)out_size; (void)ws_size;
    const float* x     = (const float*)d_in[0];
    const unsigned char* maskb = (const unsigned char*)d_in[1];
    const float* wq    = (const float*)d_in[2];
    const float* wk    = (const float*)d_in[3];
    const float* wv    = (const float*)d_in[4];
    const float* wf    = (const float*)d_in[5];
    const float* gamma = (const float*)d_in[6];
    const float* beta  = (const float*)d_in[7];

    float* ws = (float*)d_ws;
    float* MF = ws;                             // 8192
    float* D  = MF + BT;                        // 96*1024
    float* Q  = D + (size_t)96 * NT;            // 8192*768 (becomes A)
    float* K  = Q + (size_t)BT * ND;            // 8192*768
    float* V  = K + (size_t)BT * ND;            // 8192*768
    float* Y  = (float*)d_out;                  // total ws: 75.9 MB

    mask_k<<<1, 256, 0, stream>>>(maskb, MF);
    gemmseq<<<dim3(64, 12), 256, 0, stream>>>(x, wq, nullptr, Q);
    gemmseq<<<dim3(64, 12), 256, 0, stream>>>(x, wk, nullptr, K);
    gemmseq<<<dim3(64, 12), 256, 0, stream>>>(x, wv, nullptr, V);
    denom_np<<<768, 128, 0, stream>>>(Q, K, MF, D);
    attn_np<<<768, 128, 0, stream>>>(K, V, D, MF, Q);  // Q -> A
    gemmseq<<<dim3(64, 12), 256, 0, stream>>>(Q, wf, x, Y);
    rownorm_np<<<2048, 256, 0, stream>>>(Y, gamma, beta);
}